// Round 1
// baseline (427.847 us; speedup 1.0000x reference)
//
#include <hip/hip_runtime.h>

// FourierELU: out = D · elu(U · x) along axis 2 (length 8), fibers strided by
// 64*64=4096 floats. U (16x8) and D (8x16) are the analytic composites of
// rfft->pad->irfft(16) and rfft(16)->slice->irfft(8).
//
// U[m][j] = S((m-2j)&15)/16,  S(d) = 1 + 2*sum_{k=1..4} cos(pi*k*d/8)
// D[i][m] = T((2i-m)&15)/8,   T(e) = 1 + 2*sum_{k=1..3} cos(pi*k*e/8) + cos(pi*e/2)
// T(e)=0 for even e!=0, T(0)=8  =>  even-m columns of D are a passthrough.

namespace {

// S(d)/16
constexpr float US[16] = {
    0.5625f,                  0.31420871825786550f,  -0.0625f, -0.09353786016659306f,
    0.0625f,                  0.04176116486995618f,  -0.0625f, -0.01243202296122862f,
    0.0625f,                 -0.01243202296122862f,  -0.0625f,  0.04176116486995618f,
    0.0625f,                 -0.09353786016659306f,  -0.0625f,  0.31420871825786550f};

// T(e)/8 (only odd e ever indexed; even entries are the passthrough/zeros)
constexpr float DS[16] = {
    1.0f,                     0.62841743651573101f,   0.0f,    -0.18707572033318612f,
    0.0f,                     0.08352232973991236f,   0.0f,    -0.02486404592245725f,
    0.0f,                    -0.02486404592245725f,   0.0f,     0.08352232973991236f,
    0.0f,                    -0.18707572033318612f,   0.0f,     0.62841743651573101f};

}  // namespace

__device__ __forceinline__ float elu1(float v) {
  return v > 0.0f ? v : __expf(v) - 1.0f;
}

// One thread handles 4 consecutive fibers (one float4 per g-slice).
// Plane (h*w) = 4096 floats = 1024 float4s; blocks never straddle an outer.
__global__ __launch_bounds__(256) void fourier_elu_kernel(
    const float4* __restrict__ x, float4* __restrict__ out, int nquads) {
  const int idx = blockIdx.x * 256 + threadIdx.x;
  if (idx >= nquads) return;
  const int outer = idx >> 10;   // b*64 + c
  const int q     = idx & 1023;  // float4 index within the 64x64 plane
  const int base  = outer * (8 * 1024) + q;  // max 16.7M, fits int

  float4 xv[8];
#pragma unroll
  for (int g = 0; g < 8; ++g) xv[g] = x[base + g * 1024];

  float4 acc[8];
#pragma unroll
  for (int i = 0; i < 8; ++i) acc[i] = make_float4(0.f, 0.f, 0.f, 0.f);

#pragma unroll
  for (int m = 0; m < 16; ++m) {
    float4 y = make_float4(0.f, 0.f, 0.f, 0.f);
#pragma unroll
    for (int j = 0; j < 8; ++j) {
      const float u = US[(m - 2 * j) & 15];
      y.x = fmaf(u, xv[j].x, y.x);
      y.y = fmaf(u, xv[j].y, y.y);
      y.z = fmaf(u, xv[j].z, y.z);
      y.w = fmaf(u, xv[j].w, y.w);
    }
    float4 z;
    z.x = elu1(y.x);
    z.y = elu1(y.y);
    z.z = elu1(y.z);
    z.w = elu1(y.w);
    if (m & 1) {
      // odd m: dense column of D
#pragma unroll
      for (int i = 0; i < 8; ++i) {
        const float d = DS[(2 * i - m) & 15];
        acc[i].x = fmaf(d, z.x, acc[i].x);
        acc[i].y = fmaf(d, z.y, acc[i].y);
        acc[i].z = fmaf(d, z.z, acc[i].z);
        acc[i].w = fmaf(d, z.w, acc[i].w);
      }
    } else {
      // even m: passthrough to i = m/2 with weight 1
      const int i = m >> 1;
      acc[i].x += z.x;
      acc[i].y += z.y;
      acc[i].z += z.z;
      acc[i].w += z.w;
    }
  }

#pragma unroll
  for (int i = 0; i < 8; ++i) out[base + i * 1024] = acc[i];
}

extern "C" void kernel_launch(void* const* d_in, const int* in_sizes, int n_in,
                              void* d_out, int out_size, void* d_ws, size_t ws_size,
                              hipStream_t stream) {
  const float* x = (const float*)d_in[0];
  float* out = (float*)d_out;
  const int total = in_sizes[0];      // 32*64*8*64*64 = 67,108,864
  const int nquads = total / 32;      // 8 g-slices * 4 floats per thread
  const int blocks = (nquads + 255) / 256;
  fourier_elu_kernel<<<blocks, 256, 0, stream>>>((const float4*)x, (float4*)out,
                                                 nquads);
}